// Round 1
// baseline (341.329 us; speedup 1.0000x reference)
//
#include <hip/hip_runtime.h>
#include <math.h>

// Problem constants (from reference): B=64, Q=4096, N=256, 20 fg classes + 1 bg.
#define BQ 64
#define QQ 4096
#define NN 256
#define NC 20
#define NL 21
#define TQ 256   // queries per block tile

// LDS record per q: [0..2]=pred center, [3]=vol1, [4..6]=min1, [7..9]=max1,
// [10..29]=-softmax_probs (class cost), stride 32 floats.
__global__ __launch_bounds__(256)
void matcher_kernel(const float* __restrict__ logits,
                    const float* __restrict__ pboxes,
                    const int*   __restrict__ tlabels,
                    const float* __restrict__ tboxes,
                    float* __restrict__ out) {
    __shared__ float smq[TQ * 32];   // 32 KB
    const int tid = threadIdx.x;
    const int b   = blockIdx.y;
    const int q0  = blockIdx.x * TQ;

    // ---- stage per-q data: one q per thread, done once per q globally ----
    {
        const int q = q0 + tid;
        const float* lg = logits + (size_t)(b * QQ + q) * NL;
        float l[NL];
        #pragma unroll
        for (int c = 0; c < NL; ++c) l[c] = lg[c];
        float m = l[0];
        #pragma unroll
        for (int c = 1; c < NL; ++c) m = fmaxf(m, l[c]);
        float e[NL];
        float s = 0.f;
        #pragma unroll
        for (int c = 0; c < NL; ++c) { e[c] = expf(l[c] - m); s += e[c]; }
        const float rs = 1.0f / s;

        const float* pb = pboxes + (size_t)(b * QQ + q) * 6;
        float pcx = pb[0], pcy = pb[1], pcz = pb[2];
        float psx = pb[3], psy = pb[4], psz = pb[5];
        float* rec = smq + tid * 32;
        rec[0] = pcx; rec[1] = pcy; rec[2] = pcz;
        rec[3] = psx * psy * psz;
        rec[4] = pcx - psx * 0.5f; rec[5] = pcy - psy * 0.5f; rec[6] = pcz - psz * 0.5f;
        rec[7] = pcx + psx * 0.5f; rec[8] = pcy + psy * 0.5f; rec[9] = pcz + psz * 0.5f;
        #pragma unroll
        for (int c = 0; c < NC; ++c) rec[10 + c] = -(e[c] * rs);
    }

    // ---- per-thread target data (n == tid), lives in registers ----
    const float* tb = tboxes + (size_t)(b * NN + tid) * 6;
    const float tcx = tb[0], tcy = tb[1], tcz = tb[2];
    const float tsx = tb[3], tsy = tb[4], tsz = tb[5];
    const float tminx = tcx - tsx * 0.5f, tminy = tcy - tsy * 0.5f, tminz = tcz - tsz * 0.5f;
    const float tmaxx = tcx + tsx * 0.5f, tmaxy = tcy + tsy * 0.5f, tmaxz = tcz + tsz * 0.5f;
    const float vol2  = tsx * tsy * tsz;
    const int   lab   = tlabels[b * NN + tid];

    __syncthreads();

    float* op = out + (size_t)(b * QQ + q0) * NN + tid;
    #pragma unroll 4
    for (int qq = 0; qq < TQ; ++qq) {
        const float* rec = smq + qq * 32;        // wave-uniform -> LDS broadcast
        const float pcx = rec[0], pcy = rec[1], pcz = rec[2], vol1 = rec[3];
        const float mnx = rec[4], mny = rec[5], mnz = rec[6];
        const float mxx = rec[7], mxy = rec[8], mxz = rec[9];
        const float negp = rec[10 + lab];        // distinct banks or broadcast

        // center distance: strict fp32, numpy op order, no FMA contraction.
        // The dist<=2 gate selects between ~O(10) and 1e6 -> must match ref.
        const float dx = __fsub_rn(pcx, tcx);
        const float dy = __fsub_rn(pcy, tcy);
        const float dz = __fsub_rn(pcz, tcz);
        const float d2 = __fadd_rn(__fadd_rn(__fmul_rn(dx, dx), __fmul_rn(dy, dy)),
                                   __fmul_rn(dz, dz));
        const float dist = __fsqrt_rn(d2);

        // 3D IoU (continuous -> approx rcp is fine; union > 0 always since sizes>=0.5)
        const float ix = fmaxf(fminf(mxx, tmaxx) - fmaxf(mnx, tminx), 0.f);
        const float iy = fmaxf(fminf(mxy, tmaxy) - fmaxf(mny, tminy), 0.f);
        const float iz = fmaxf(fminf(mxz, tmaxz) - fmaxf(mnz, tminz), 0.f);
        const float iv  = ix * iy * iz;
        const float uni = vol1 + vol2 - iv;
        const float iou = iv * __frcp_rn(uni);

        const float t = negp + 5.0f * dist + 2.0f - 2.0f * iou;
        const float r = (dist <= 2.0f) ? t : 1000000.0f;

        op[(size_t)qq * NN] = r;                 // coalesced along n
    }
}

extern "C" void kernel_launch(void* const* d_in, const int* in_sizes, int n_in,
                              void* d_out, int out_size, void* d_ws, size_t ws_size,
                              hipStream_t stream) {
    const float* logits = (const float*)d_in[0];   // (B,Q,21)
    const float* pboxes = (const float*)d_in[1];   // (B,Q,6)
    const int*   tlabels = (const int*)d_in[2];    // (B,N)
    const float* tboxes = (const float*)d_in[3];   // (B,N,6)
    float* out = (float*)d_out;                    // (B,Q,N) fp32

    dim3 grid(QQ / TQ, BQ);
    matcher_kernel<<<grid, dim3(256), 0, stream>>>(logits, pboxes, tlabels, tboxes, out);
}

// Round 3
// 302.815 us; speedup vs baseline: 1.1272x; 1.1272x over previous
//
#include <hip/hip_runtime.h>
#include <math.h>

// B=64, Q=4096, N=256, 20 fg classes + 1 bg. Output (B,Q,N) fp32 = 268 MB.
#define BQ 64
#define QQ 4096
#define NN 256
#define NC 20
#define NL 21
#define TQ 256          // queries per block
#define GEO_STRIDE 12   // 10 floats used + 2 pad -> 48 B, 16-B aligned (ds_read_b128)
#define PROB_STRIDE 257 // 256+1: label gather hits 20 distinct banks; staging writes conflict-free

// Gate: sqrt_rn(d2) <= 2.0  <=>  d2 <= 4 + ulp(4).
// (d2 = 4+ulp(4): true sqrt < midpoint(2.0, nextafter) -> rounds to 2.0 -> true;
//  d2 = 4+2ulp(4): true sqrt > midpoint -> rounds above 2.0 -> false.)
#define GATE_D2 0x1.000001p+2f

__global__ __launch_bounds__(256)
void matcher_kernel(const float* __restrict__ logits,
                    const float* __restrict__ pboxes,
                    const int*   __restrict__ tlabels,
                    const float* __restrict__ tboxes,
                    float* __restrict__ out) {
    __shared__ __align__(16) float geo[TQ * GEO_STRIDE];    // 12 KB
    __shared__ float prob[NC * PROB_STRIDE];                // 20.1 KB -> ~32.2 KB total
    const int tid = threadIdx.x;
    const int b   = blockIdx.y;
    const int q0  = blockIdx.x * TQ;

    // ---- staging: one q per thread (softmax once per q, not per (q,n)) ----
    {
        const int q = q0 + tid;
        const float* lg = logits + (size_t)(b * QQ + q) * NL;
        float l[NL];
        #pragma unroll
        for (int c = 0; c < NL; ++c) l[c] = lg[c];
        float m = l[0];
        #pragma unroll
        for (int c = 1; c < NL; ++c) m = fmaxf(m, l[c]);
        float e[NL];
        float s = 0.f;
        #pragma unroll
        for (int c = 0; c < NL; ++c) { e[c] = expf(l[c] - m); s += e[c]; }
        const float rs = 1.0f / s;      // once per q; class cost is continuous
        #pragma unroll
        for (int c = 0; c < NC; ++c)    // bank (c+tid)%32 -> 2 lanes/bank (free)
            prob[c * PROB_STRIDE + tid] = -(e[c] * rs);

        const float* pb = pboxes + (size_t)(b * QQ + q) * 6;
        const float pcx = pb[0], pcy = pb[1], pcz = pb[2];
        const float psx = pb[3], psy = pb[4], psz = pb[5];
        float4* gp = (float4*)(geo + tid * GEO_STRIDE);
        gp[0] = make_float4(pcx, pcy, pcz, psx * psy * psz);
        gp[1] = make_float4(pcx - psx * 0.5f, pcy - psy * 0.5f, pcz - psz * 0.5f, 0.f);
        gp[2] = make_float4(pcx + psx * 0.5f, pcy + psy * 0.5f, pcz + psz * 0.5f, 0.f);
    }

    // ---- per-thread: quad of targets n0..n0+3 lives in registers ----
    const int lane = tid & 63;
    const int w    = tid >> 6;
    const int n0   = lane * 4;
    float tcx[4], tcy[4], tcz[4];
    float mn_x[4], mn_y[4], mn_z[4], mx_x[4], mx_y[4], mx_z[4], v2[4];
    int plab[4];
    #pragma unroll
    for (int j = 0; j < 4; ++j) {
        const float* tb = tboxes + (size_t)(b * NN + n0 + j) * 6;
        const float cx = tb[0], cy = tb[1], cz = tb[2];
        const float sx = tb[3], sy = tb[4], sz = tb[5];
        tcx[j] = cx; tcy[j] = cy; tcz[j] = cz;
        mn_x[j] = cx - sx * 0.5f; mn_y[j] = cy - sy * 0.5f; mn_z[j] = cz - sz * 0.5f;
        mx_x[j] = cx + sx * 0.5f; mx_y[j] = cy + sy * 0.5f; mx_z[j] = cz + sz * 0.5f;
        v2[j]   = sx * sy * sz;
        plab[j] = tlabels[b * NN + n0 + j] * PROB_STRIDE;
    }

    __syncthreads();

    // Each wave handles qq = w, w+4, ...; one dwordx4 store per wave-iter
    // covers a full contiguous 1-KB q-row of the output.
    float* ob = out + ((size_t)(b * QQ + q0)) * NN + n0;
    #pragma unroll 2
    for (int qq = w; qq < TQ; qq += 4) {
        const float4* gp = (const float4*)(geo + qq * GEO_STRIDE); // wave-uniform broadcast
        const float4 g0 = gp[0];   // pc.xyz, vol1
        const float4 g1 = gp[1];   // min1.xyz
        const float4 g2 = gp[2];   // max1.xyz
        float r[4];
        #pragma unroll
        for (int j = 0; j < 4; ++j) {
            const float negp = prob[plab[j] + qq];   // distinct banks per distinct label

            // strict fp32, numpy op order, no FMA: feeds the 1e6 discontinuity gate
            const float dx = __fsub_rn(g0.x, tcx[j]);
            const float dy = __fsub_rn(g0.y, tcy[j]);
            const float dz = __fsub_rn(g0.z, tcz[j]);
            const float d2 = __fadd_rn(__fadd_rn(__fmul_rn(dx, dx), __fmul_rn(dy, dy)),
                                       __fmul_rn(dz, dz));
            const float dist = __builtin_amdgcn_sqrtf(d2);   // 1-ulp v_sqrt: continuous term only

            const float ix = fmaxf(fminf(g2.x, mx_x[j]) - fmaxf(g1.x, mn_x[j]), 0.f);
            const float iy = fmaxf(fminf(g2.y, mx_y[j]) - fmaxf(g1.y, mn_y[j]), 0.f);
            const float iz = fmaxf(fminf(g2.z, mx_z[j]) - fmaxf(g1.z, mn_z[j]), 0.f);
            const float iv  = ix * iy * iz;
            const float uni = g0.w + v2[j] - iv;     // > 0 always (sizes >= 0.5)
            const float iou = iv * __builtin_amdgcn_rcpf(uni);  // 1-ulp v_rcp

            const float t = fmaf(5.0f, dist, negp) + fmaf(-2.0f, iou, 2.0f);
            r[j] = (d2 <= GATE_D2) ? t : 1000000.0f; // bit-exact gate (see GATE_D2)
        }
        *(float4*)(ob + (size_t)qq * NN) = make_float4(r[0], r[1], r[2], r[3]);
    }
}

extern "C" void kernel_launch(void* const* d_in, const int* in_sizes, int n_in,
                              void* d_out, int out_size, void* d_ws, size_t ws_size,
                              hipStream_t stream) {
    const float* logits  = (const float*)d_in[0];  // (B,Q,21)
    const float* pboxes  = (const float*)d_in[1];  // (B,Q,6)
    const int*   tlabels = (const int*)d_in[2];    // (B,N)
    const float* tboxes  = (const float*)d_in[3];  // (B,N,6)
    float* out = (float*)d_out;                    // (B,Q,N) fp32

    dim3 grid(QQ / TQ, BQ);                        // 16 x 64 = 1024 blocks = 4/CU
    matcher_kernel<<<grid, dim3(256), 0, stream>>>(logits, pboxes, tlabels, tboxes, out);
}

// Round 4
// 295.282 us; speedup vs baseline: 1.1559x; 1.0255x over previous
//
#include <hip/hip_runtime.h>
#include <math.h>

// B=64, Q=4096, N=256, 20 fg classes + 1 bg. Output (B,Q,N) fp32 = 268 MB.
// KEY SPARSITY FACT: centers uniform in [0,50]^3, gate radius 2.0 ->
// P(dist<=2) ~ 0.027%; P(any of a wave-iter's 256 pairs active) ~ 6.5%.
// 93% of wave-iters take a d2-only fast path and store constant 1e6.
#define BQ 64
#define QQ 4096
#define NN 256
#define NC 20
#define NL 21
#define TQ 256          // queries per block
#define GEO_STRIDE 12   // 10 floats used + 2 pad -> 48 B, 16-B aligned (ds_read_b128)
#define PROB_STRIDE 257 // label gather hits distinct banks; staging writes conflict-free

// Gate: sqrt_rn(d2) <= 2.0  <=>  d2 <= 4 + ulp(4)  (bit-exact vs numpy fp32).
#define GATE_D2 0x1.000001p+2f

__global__ __launch_bounds__(256)
void matcher_kernel(const float* __restrict__ logits,
                    const float* __restrict__ pboxes,
                    const int*   __restrict__ tlabels,
                    const float* __restrict__ tboxes,
                    float* __restrict__ out) {
    __shared__ __align__(16) float geo[TQ * GEO_STRIDE];    // 12 KB
    __shared__ float prob[NC * PROB_STRIDE];                // 20.1 KB
    const int tid = threadIdx.x;
    const int b   = blockIdx.y;
    const int q0  = blockIdx.x * TQ;

    // ---- staging: one q per thread (softmax once per q) ----
    {
        const int q = q0 + tid;
        const float* lg = logits + (size_t)(b * QQ + q) * NL;
        float l[NL];
        #pragma unroll
        for (int c = 0; c < NL; ++c) l[c] = lg[c];
        float m = l[0];
        #pragma unroll
        for (int c = 1; c < NL; ++c) m = fmaxf(m, l[c]);
        float e[NL];
        float s = 0.f;
        #pragma unroll
        for (int c = 0; c < NL; ++c) { e[c] = expf(l[c] - m); s += e[c]; }
        const float rs = 1.0f / s;
        #pragma unroll
        for (int c = 0; c < NC; ++c)    // bank (c+tid)%32 -> 2 lanes/bank (free)
            prob[c * PROB_STRIDE + tid] = -(e[c] * rs);

        const float* pb = pboxes + (size_t)(b * QQ + q) * 6;
        const float pcx = pb[0], pcy = pb[1], pcz = pb[2];
        const float psx = pb[3], psy = pb[4], psz = pb[5];
        float4* gp = (float4*)(geo + tid * GEO_STRIDE);
        gp[0] = make_float4(pcx, pcy, pcz, psx * psy * psz);
        gp[1] = make_float4(pcx - psx * 0.5f, pcy - psy * 0.5f, pcz - psz * 0.5f, 0.f);
        gp[2] = make_float4(pcx + psx * 0.5f, pcy + psy * 0.5f, pcz + psz * 0.5f, 0.f);
    }

    // ---- per-thread: quad of targets n0..n0+3 in registers ----
    const int lane = tid & 63;
    const int w    = tid >> 6;
    const int n0   = lane * 4;
    float tcx[4], tcy[4], tcz[4];
    float mn_x[4], mn_y[4], mn_z[4], mx_x[4], mx_y[4], mx_z[4], v2[4];
    int plab[4];
    #pragma unroll
    for (int j = 0; j < 4; ++j) {
        const float* tb = tboxes + (size_t)(b * NN + n0 + j) * 6;
        const float cx = tb[0], cy = tb[1], cz = tb[2];
        const float sx = tb[3], sy = tb[4], sz = tb[5];
        tcx[j] = cx; tcy[j] = cy; tcz[j] = cz;
        mn_x[j] = cx - sx * 0.5f; mn_y[j] = cy - sy * 0.5f; mn_z[j] = cz - sz * 0.5f;
        mx_x[j] = cx + sx * 0.5f; mx_y[j] = cy + sy * 0.5f; mx_z[j] = cz + sz * 0.5f;
        v2[j]   = sx * sy * sz;
        plab[j] = tlabels[b * NN + n0 + j] * PROB_STRIDE;
    }

    __syncthreads();

    const float4 MISS = make_float4(1000000.0f, 1000000.0f, 1000000.0f, 1000000.0f);
    float* ob = out + ((size_t)(b * QQ + q0)) * NN + n0;

    // Each wave handles qq = w, w+4, ... One dwordx4 store per wave-iter
    // covers a contiguous 1-KB q-row (coalesced). Fast path: d2 + gate only.
    for (int qq = w; qq < TQ; qq += 4) {
        const float4* gp = (const float4*)(geo + qq * GEO_STRIDE); // uniform broadcast
        const float4 g0 = gp[0];   // pc.xyz, vol1

        // strict fp32, numpy op order, no FMA: feeds the 1e6 discontinuity gate
        float d2v[4];
        int active = 0;
        #pragma unroll
        for (int j = 0; j < 4; ++j) {
            const float dx = __fsub_rn(g0.x, tcx[j]);
            const float dy = __fsub_rn(g0.y, tcy[j]);
            const float dz = __fsub_rn(g0.z, tcz[j]);
            d2v[j] = __fadd_rn(__fadd_rn(__fmul_rn(dx, dx), __fmul_rn(dy, dy)),
                               __fmul_rn(dz, dz));
            active |= (d2v[j] <= GATE_D2);
        }

        float4* orow = (float4*)(ob + (size_t)qq * NN);
        if (!__any(active)) {          // wave-uniform: ~93% of iters
            *orow = MISS;
            continue;
        }

        const float4 g1 = gp[1];       // min1.xyz
        const float4 g2 = gp[2];       // max1.xyz
        float r[4];
        #pragma unroll
        for (int j = 0; j < 4; ++j) {
            const float negp = prob[plab[j] + qq];

            const float dist = __builtin_amdgcn_sqrtf(d2v[j]); // continuous term only

            const float ix = fmaxf(fminf(g2.x, mx_x[j]) - fmaxf(g1.x, mn_x[j]), 0.f);
            const float iy = fmaxf(fminf(g2.y, mx_y[j]) - fmaxf(g1.y, mn_y[j]), 0.f);
            const float iz = fmaxf(fminf(g2.z, mx_z[j]) - fmaxf(g1.z, mn_z[j]), 0.f);
            const float iv  = ix * iy * iz;
            const float uni = g0.w + v2[j] - iv;     // > 0 always (sizes >= 0.5)
            const float iou = iv * __builtin_amdgcn_rcpf(uni);

            const float t = fmaf(5.0f, dist, negp) + fmaf(-2.0f, iou, 2.0f);
            r[j] = (d2v[j] <= GATE_D2) ? t : 1000000.0f;   // bit-exact gate
        }
        *orow = make_float4(r[0], r[1], r[2], r[3]);
    }
}

extern "C" void kernel_launch(void* const* d_in, const int* in_sizes, int n_in,
                              void* d_out, int out_size, void* d_ws, size_t ws_size,
                              hipStream_t stream) {
    const float* logits  = (const float*)d_in[0];  // (B,Q,21)
    const float* pboxes  = (const float*)d_in[1];  // (B,Q,6)
    const int*   tlabels = (const int*)d_in[2];    // (B,N)
    const float* tboxes  = (const float*)d_in[3];  // (B,N,6)
    float* out = (float*)d_out;                    // (B,Q,N) fp32

    dim3 grid(QQ / TQ, BQ);                        // 16 x 64 = 1024 blocks = 4/CU
    matcher_kernel<<<grid, dim3(256), 0, stream>>>(logits, pboxes, tlabels, tboxes, out);
}